// Round 1
// baseline (158.085 us; speedup 1.0000x reference)
//
#include <hip/hip_runtime.h>

// Problem constants (fixed by setup_inputs):
//   tensor  [B=8, C=64, H=256, W=256] float32
//   centers [B=8, N=512, 2] int32 (y, x) in [0, 256)
//   patch 16x16, pad 8 -> out[b][n][c][i][j] = in-bounds ? tensor[b][c][cy+i-8][cx+j-8] : 0
//   out     [B=8, N=512, C=64, 16, 16] float32 (67,108,864 elems, 256 MB)

#define B_ 8
#define C_ 64
#define H_ 256
#define W_ 256
#define N_ 512

__global__ __launch_bounds__(256) void patch_extract_kernel(
    const float* __restrict__ in,
    const int* __restrict__ centers,
    float* __restrict__ out)
{
    // One block = one (b, n, c) 16x16 patch plane; 256 threads = 16x16 elems.
    const int blk = blockIdx.x;            // b*N*C + n*C + c
    const int c = blk & (C_ - 1);          // blk % 64
    const int n = (blk >> 6) & (N_ - 1);   // (blk / 64) % 512
    const int b = blk >> 15;               // blk / (64*512)

    const int t = threadIdx.x;
    const int j = t & 15;                  // patch col
    const int i = t >> 4;                  // patch row

    // Block-uniform center read -> scalar broadcast.
    const int cy = centers[((b * N_ + n) << 1) + 0];
    const int cx = centers[((b * N_ + n) << 1) + 1];

    const int y = cy + i - 8;
    const int x = cx + j - 8;

    float v = 0.0f;
    if ((unsigned)y < (unsigned)H_ && (unsigned)x < (unsigned)W_) {
        // in[((b*C + c) * H + y) * W + x]
        v = in[((((size_t)(b * C_ + c)) << 8) + (size_t)y) * (size_t)W_ + (size_t)x];
    }

    // out[blk*256 + t] -- fully coalesced contiguous store.
    out[((size_t)blk << 8) + (size_t)t] = v;
}

extern "C" void kernel_launch(void* const* d_in, const int* in_sizes, int n_in,
                              void* d_out, int out_size, void* d_ws, size_t ws_size,
                              hipStream_t stream) {
    const float* tensor  = (const float*)d_in[0];
    const int*   centers = (const int*)d_in[1];
    float*       out     = (float*)d_out;

    const int nblocks = B_ * N_ * C_;  // 262144
    patch_extract_kernel<<<nblocks, 256, 0, stream>>>(tensor, centers, out);
}

// Round 2
// 141.816 us; speedup vs baseline: 1.1147x; 1.1147x over previous
//
#include <hip/hip_runtime.h>

// Problem constants (fixed by setup_inputs):
//   tensor  [B=8, C=64, H=256, W=256] float32
//   centers [B=8, N=512, 2] int32 (y, x) in [0, 256)
//   patch 16x16, pad 8 -> out[b][n][c][i][j] = in-bounds ? tensor[b][c][cy+i-8][cx+j-8] : 0
//   out     [B=8, N=512, C=64, 16, 16] float32 (256 MB)
//
// Design (round 2): one block per (b, n) patch. 4096 blocks x 256 threads.
// Each block writes a contiguous 64 KB chunk of out. Thread t handles, per
// iteration, 4 consecutive output floats (one quarter of a patch row of one
// channel) -> 16 iterations cover 64 channels. Stores are nontemporal
// dwordx4 (output never re-read; keep L3 for the tensor). Reads are 4
// predicated dword loads per lane; a 4-lane group covers one 64 B patch row
// contiguously (coalesced), and each wave covers exactly one channel per
// iteration.

#define B_ 8
#define C_ 64
#define H_ 256
#define W_ 256
#define N_ 512

typedef float f32x4 __attribute__((ext_vector_type(4)));

__global__ __launch_bounds__(256) void patch_extract_kernel(
    const float* __restrict__ in,
    const int* __restrict__ centers,
    float* __restrict__ out)
{
    const int bn = blockIdx.x;            // b*N + n
    const int b  = bn >> 9;               // bn / 512
    const int t  = threadIdx.x;

    // Block-uniform -> scalar loads.
    const int cy = centers[(bn << 1) + 0];
    const int cx = centers[(bn << 1) + 1];

    const int i  = (t >> 2) & 15;         // patch row
    const int j0 = (t & 3) << 2;          // patch col start: 0,4,8,12
    const int w  = t >> 6;                // wave id 0..3 -> channel offset

    const int y   = cy + i - 8;
    const bool yin = (unsigned)y < (unsigned)H_;
    const int x0  = cx + j0 - 8;

    const float* inb = in + ((long long)b * C_ * H_ * W_);
    float* outb = out + ((long long)bn << 14) + ((long long)t << 2);

    #pragma unroll 4
    for (int iter = 0; iter < 16; ++iter) {
        const int c = (iter << 2) + w;    // this wave's channel this iteration
        const float* row = inb + ((long long)c * (H_ * W_)) + (long long)y * W_;

        f32x4 v;
        #pragma unroll
        for (int l = 0; l < 4; ++l) {
            const int x = x0 + l;
            float f = 0.0f;
            if (yin && (unsigned)x < (unsigned)W_) f = row[x];
            v[l] = f;
        }
        __builtin_nontemporal_store(v, (f32x4*)(outb + ((long long)iter << 10)));
    }
}

extern "C" void kernel_launch(void* const* d_in, const int* in_sizes, int n_in,
                              void* d_out, int out_size, void* d_ws, size_t ws_size,
                              hipStream_t stream) {
    const float* tensor  = (const float*)d_in[0];
    const int*   centers = (const int*)d_in[1];
    float*       out     = (float*)d_out;

    patch_extract_kernel<<<B_ * N_, 256, 0, stream>>>(tensor, centers, out);
}

// Round 3
// 124.332 us; speedup vs baseline: 1.2715x; 1.1406x over previous
//
#include <hip/hip_runtime.h>

// Problem constants (fixed by setup_inputs):
//   tensor  [B=8, C=64, H=256, W=256] float32
//   centers [B=8, N=512, 2] int32 (y, x) in [0, 256)
//   patch 16x16, pad 8 -> out[b][n][c][i][j] = in-bounds ? tensor[b][c][cy+i-8][cx+j-8] : 0
//   out     [B=8, N=512, C=64, 16, 16] float32 (256 MB)
//
// Design (round 3): one block per (b, n, channel-group-of-8). Grid = 32768.
// Channel group g = blockIdx.x & 7 so the default round-robin block->XCD
// mapping pins plane set [8g, 8g+8) to XCD g (round-1 evidence: this
// partitioning gave FETCH=71MB vs round-2's 302MB when every XCD read every
// plane). Each block writes an 8 KB contiguous output chunk: 2 nontemporal
// dwordx4 stores per thread. Reads: 4 predicated dword loads per lane; one
// wave covers one channel's full 16x16 patch per pass.

#define B_ 8
#define C_ 64
#define H_ 256
#define W_ 256
#define N_ 512

typedef float f32x4 __attribute__((ext_vector_type(4)));

__global__ __launch_bounds__(256) void patch_extract_kernel(
    const float* __restrict__ in,
    const int* __restrict__ centers,
    float* __restrict__ out)
{
    const int blk = blockIdx.x;
    const int g   = blk & 7;          // channel group -> XCD (round-robin)
    const int bn  = blk >> 3;         // b*N + n
    const int b   = bn >> 9;          // bn / 512
    const int t   = threadIdx.x;

    // Block-uniform -> scalar broadcast loads.
    const int cy = centers[(bn << 1) + 0];
    const int cx = centers[(bn << 1) + 1];

    // Base of this block's 8 channel planes.
    const float* inb = in + ((long long)b * (C_ * H_ * W_)) + (((long long)g * 8) << 16);
    // Base of this block's contiguous 8 KB output chunk.
    float* outc = out + ((long long)bn << 14) + (((long long)g * 8) << 8);

    #pragma unroll
    for (int p = 0; p < 2; ++p) {
        const int q       = (p << 8) + t;   // quad index 0..511 within chunk
        const int c_local = q >> 6;         // 0..7 (wave-uniform)
        const int rem     = q & 63;
        const int i       = rem >> 2;       // patch row 0..15
        const int j0      = (rem & 3) << 2; // patch col start: 0,4,8,12

        const int y   = cy + i - 8;
        const int x0  = cx + j0 - 8;
        const bool yin = (unsigned)y < (unsigned)H_;

        const float* row = inb + ((long long)c_local << 16) + (long long)y * W_;

        f32x4 v;
        #pragma unroll
        for (int l = 0; l < 4; ++l) {
            const int x = x0 + l;
            float f = 0.0f;
            if (yin && (unsigned)x < (unsigned)W_) f = row[x];
            v[l] = f;
        }
        // Output is never re-read: bypass cache, keep L2/L3 for the tensor.
        __builtin_nontemporal_store(v, (f32x4*)(outc + ((long long)q << 2)));
    }
}

extern "C" void kernel_launch(void* const* d_in, const int* in_sizes, int n_in,
                              void* d_out, int out_size, void* d_ws, size_t ws_size,
                              hipStream_t stream) {
    const float* tensor  = (const float*)d_in[0];
    const int*   centers = (const int*)d_in[1];
    float*       out     = (float*)d_out;

    patch_extract_kernel<<<B_ * N_ * 8, 256, 0, stream>>>(tensor, centers, out);
}